// Round 16
// baseline (153.876 us; speedup 1.0000x reference)
//
#include <hip/hip_runtime.h>
#include <hip/hip_bf16.h>
#include <math.h>

// Leapfrog on SPD(32), eigh-free, inverse-free, barrier-free MFMA version.
//   U = S·P ; Ut = P·S (independent) ; H = U·U (= S·P·S·P = S·G)
//   M = 0.02·U - 2e-4·H  (= 2DT·S·pi_half)
//   E = exp(M^T) Taylor-3, first stage in f32 VALU: X3 = I + M/3,
//   then X2 = I + (1/2)M^T·X3, X1 = I + M^T·X2 (2 MFMA stages)
//   Sigma_new = sym(S·E) + 1e-8 I
// R14 body + THE FIX: the LDS transpose-bounce reads other lanes' writes,
// which is invisible to the compiler's per-thread memory model (write and
// read don't alias per-thread) -> it may legally reorder ds_reads before
// ds_writes. R15's 16-wave codegen did exactly that (absmax 1.7); R7/R8's
// region-reuse variant hit the same class (bit-identical 0.09375 across
// different rounding). __threadfence_block() between bounce writes and
// reads pins instruction order; the per-wave in-order DS pipe does the rest.
// With the race closed, re-run the occupancy experiment: 1024-thread
// blocks (16 waves), __launch_bounds__(1024,8) forces VGPR<=64 (R14's
// natural count) -> 2 blocks/CU = 32 waves resident (LDS 67.6KB/block).
// All validated pieces kept: trunc v_perm packs, LDS-bounce sym epilogue
// (contiguous stores), cached loads, nt stores only, U^2-head, Taylor-3
// with f32 first stage, independent 3-chain tail, v_permlane32_swap_b32
// B-frag exchange (swap32(x,y): x.lanes[32:63] <-> y.lanes[0:31]).

typedef unsigned int u32;
typedef __attribute__((ext_vector_type(8))) short bf16x8;
typedef __attribute__((ext_vector_type(16))) float f32x16;

#define FPAD 33   // f32 row stride of sym buffer: 33 mod 32 == 1 -> conflict-free

union U4 { u32 u[4]; bf16x8 v; };

__device__ __forceinline__ bf16x8 mk8(u32 a, u32 b, u32 c, u32 d) {
    U4 t; t.u[0] = a; t.u[1] = b; t.u[2] = c; t.u[3] = d; return t.v;
}

// pack bf16(x),bf16(y) (truncated) into one u32: low16 = x, high16 = y
__device__ __forceinline__ u32 pkt(float x, float y) {
    return __builtin_amdgcn_perm(__float_as_uint(y), __float_as_uint(x), 0x07060302u);
}

__device__ __forceinline__ float asfloat(u32 b) {
    union { u32 u; float f; } c; c.u = b; return c.f;
}

__device__ __forceinline__ f32x16 zero16() {
    f32x16 z;
#pragma unroll
    for (int i = 0; i < 16; ++i) z[i] = 0.f;
    return z;
}

struct Frag8 { u32 r[8]; };

// v_permlane32_swap_b32: x.lanes[32:63] <-> y.lanes[0:31]
__device__ __forceinline__ void swap32(u32& x, u32& y) {
    asm("v_permlane32_swap_b32 %0, %1" : "+v"(x), "+v"(y));
}

// packed-pair regs p[8] (D-layout pairs) -> B-fragment order.
// swap32(x=p[lo], y=p[hi]):
//   x.lanes[32:63] <- old y.lanes[0:31]  = p[hi] of lane l-32   -> x == B.r[lo]
//   y.lanes[0:31]  <- old x.lanes[32:63] = p[lo] of lane l+32   -> y == B.r[hi]
__device__ __forceinline__ void xchg(const u32* p, Frag8& B) {
    { u32 x = p[0], y = p[2]; swap32(x, y); B.r[0] = x; B.r[2] = y; }
    { u32 x = p[1], y = p[3]; swap32(x, y); B.r[1] = x; B.r[3] = y; }
    { u32 x = p[4], y = p[6]; swap32(x, y); B.r[4] = x; B.r[6] = y; }
    { u32 x = p[5], y = p[7]; swap32(x, y); B.r[5] = x; B.r[7] = y; }
}

// D-layout f32x16 -> bf16 B-fragment, trunc pack (no scale)
__device__ __forceinline__ void bconv(const f32x16& X, Frag8& B) {
    u32 p[8];
#pragma unroll
    for (int i = 0; i < 8; ++i) p[i] = pkt(X[2*i], X[2*i+1]);
    xchg(p, B);
}

// D-layout f32x16 -> bf16 B-fragment, pre-scaled, trunc pack
__device__ __forceinline__ void bconv_s(const f32x16& X, float scale, Frag8& B) {
    u32 p[8];
#pragma unroll
    for (int i = 0; i < 8; ++i) p[i] = pkt(X[2*i] * scale, X[2*i+1] * scale);
    xchg(p, B);
}

// D-layout f32x16 -> exact hi/lo split bf16 B-fragments
__device__ __forceinline__ void bconv_split(const f32x16& X, Frag8& Bh, Frag8& Bl) {
    u32 p[8], q[8];
#pragma unroll
    for (int i = 0; i < 8; ++i) {
        const float x = X[2*i], y = X[2*i+1];
        p[i] = pkt(x, y);
        const float lx = x - asfloat(p[i] << 16);
        const float ly = y - asfloat(p[i] & 0xffff0000u);
        q[i] = pkt(lx, ly);
    }
    xchg(p, Bh);
    xchg(q, Bl);
}

__device__ __forceinline__ f32x16 MFMA1(const u32* a, const u32* b, f32x16 acc) {
    return __builtin_amdgcn_mfma_f32_32x32x16_bf16(
        mk8(a[0], a[1], a[2], a[3]), mk8(b[0], b[1], b[2], b[3]), acc, 0, 0, 0);
}

__device__ __forceinline__ f32x16 matmul(const Frag8& A, const Frag8& B, f32x16 acc) {
    acc = MFMA1(A.r,     B.r,     acc);   // k = 0..15
    acc = MFMA1(A.r + 4, B.r + 4, acc);   // k = 16..31
    return acc;
}

__global__ __launch_bounds__(1024, 8)
void leapfrog_fused(const float* __restrict__ Sg, const float* __restrict__ Pg,
                    const float* __restrict__ phig, const float* __restrict__ piphig,
                    float* __restrict__ out, int total)
{
    __shared__ __align__(16) float symb[16 * 32 * FPAD];

    const int w  = threadIdx.x >> 6;          // 0..15
    const int l  = threadIdx.x & 63;
    const int bn = blockIdx.x * 16 + w;
    if (bn >= total) return;            // wave-uniform; kernel has no barriers

    float* sy = symb + w * 32 * FPAD;

    const int fr = l & 31;
    const int h  = l >> 5;
    const size_t gbase = (size_t)bn * 1024;

    // ---- fragment loads straight from global; phi prefetched alongside ----
    const float* Srow = Sg + gbase + fr * 32 + h * 8;
    const float* Prow = Pg + gbase + fr * 32 + h * 8;
    const float4 sv[4] = { *(const float4*)(Srow +  0), *(const float4*)(Srow +  4),
                           *(const float4*)(Srow + 16), *(const float4*)(Srow + 20) };
    const float4 pv[4] = { *(const float4*)(Prow +  0), *(const float4*)(Prow +  4),
                           *(const float4*)(Prow + 16), *(const float4*)(Prow + 20) };
    // phi inputs: lanes 0-2 each handle one component in the epilogue
    float phc = 0.f, qhc = 0.f;
    if (l < 3) { phc = phig[3 * bn + l]; qhc = piphig[3 * bn + l]; }

    Frag8 FS, FSl, FP;
#pragma unroll
    for (int i = 0; i < 4; ++i) {
        const float4 s = sv[i];
        const float4 p = pv[i];
        const u32 ha = pkt(s.x, s.y);
        const u32 hb = pkt(s.z, s.w);
        FS.r[2*i]   = ha;
        FS.r[2*i+1] = hb;
        const float lx = s.x - asfloat(ha << 16);
        const float ly = s.y - asfloat(ha & 0xffff0000u);
        const float lz = s.z - asfloat(hb << 16);
        const float lw = s.w - asfloat(hb & 0xffff0000u);
        FSl.r[2*i]   = pkt(lx, ly);
        FSl.r[2*i+1] = pkt(lz, lw);
        FP.r[2*i]   = pkt(p.x, p.y);
        FP.r[2*i+1] = pkt(p.z, p.w);
    }

    // identity in D-layout: row (i&3)+8*(i>>2)+4h, col fr
    f32x16 If;
#pragma unroll
    for (int i = 0; i < 16; ++i)
        If[i] = (((i & 3) + 8 * (i >> 2) + 4 * h) == fr) ? 1.f : 0.f;

    // ---- U = S·P ; Ut = P·S (independent chains) ; H = U·U = S·P·S·P ----
    f32x16 U  = matmul(FS, FP, zero16());
    f32x16 Ut = matmul(FP, FS, zero16());
    Frag8 BU;  bconv(U,  BU);
    Frag8 BUt; bconv(Ut, BUt);              // as A-operand represents U
    f32x16 H = matmul(BUt, BU, zero16());

    // ---- M = 2DT·U − 2DT²·H ;  X3 = I + M/3 (f32 VALU — free stage) ----
    f32x16 M, X;
#pragma unroll
    for (int i = 0; i < 16; ++i) {
        M[i] = 0.02f * U[i] - 2e-4f * H[i];
        X[i] = If[i] + (1.0f / 3.0f) * M[i];
    }
    Frag8 FM; bconv(M, FM);                 // A-frag of M^T

    // ---- X2 = I + (1/2)·M^T·X3 ; X1 = I + M^T·X2 (2 MFMA stages) ----
    {
        Frag8 BX; bconv_s(X, 0.5f, BX);
        X = matmul(FM, BX, If);
    }
    {
        Frag8 BX; bconv(X, BX);
        X = matmul(FM, BX, If);
    }

    // ---- Y^T = S·X, hi/lo split, three INDEPENDENT 2-MFMA chains ----
    Frag8 BE, BEl;
    bconv_split(X, BE, BEl);
    f32x16 Y1 = matmul(FS,  BE,  zero16());
    f32x16 Y2 = matmul(FSl, BE,  zero16());
    f32x16 Y3 = matmul(FS,  BEl, zero16());

    // ---- sym + eps·I via LDS bounce. The reads consume OTHER lanes'
    //      writes: invisible to per-thread alias analysis, so a fence is
    //      REQUIRED to stop the compiler reordering reads before writes
    //      (R15's failure). DS pipe is in-order per wave -> fence alone
    //      suffices, no __syncthreads needed (regions are per-wave). ----
#pragma unroll
    for (int i = 0; i < 16; ++i) {
        const int r = (i & 3) + 8 * (i >> 2) + 4 * h;
        sy[r * FPAD + fr] = Y1[i] + Y2[i] + Y3[i];
    }
    __threadfence_block();                  // order bounce writes before reads
    const size_t obase = (size_t)bn * 1027;
#pragma unroll
    for (int k = 0; k < 16; ++k) {
        const int idx = k * 64 + l;
        const int r = idx >> 5, c = idx & 31;
        const float a = sy[r * FPAD + c];
        const float b = sy[c * FPAD + r];
        float v = 0.5f * (a + b);
        if (r == c) v += 1e-8f;
        __builtin_nontemporal_store(v, &out[obase + idx]);
    }

    // ---- fused phi retraction (lanes 0-2, double; floor-based mod 2pi) ----
    if (l < 3) {
        const double TWO_PI = 6.283185307179586476925287;
        const double PI_    = 3.141592653589793238462643;
        const double c0 = (double)__shfl(phc, 0, 64) + 0.01 * (double)__shfl(qhc, 0, 64);
        const double c1 = (double)__shfl(phc, 1, 64) + 0.01 * (double)__shfl(qhc, 1, 64);
        const double c2 = (double)__shfl(phc, 2, 64) + 0.01 * (double)__shfl(qhc, 2, 64);
        const double me = (l == 0) ? c0 : (l == 1) ? c1 : c2;
        const double theta = sqrt(c0 * c0 + c1 * c1 + c2 * c2);
        const double ts = theta > 1e-12 ? theta : 1e-12;
        const double k2 = floor(theta * (1.0 / TWO_PI));
        const double tw = theta - k2 * TWO_PI;          // fmod(theta, 2pi), theta >= 0
        double t, sgn;
        if (tw > PI_) { t = TWO_PI - tw; sgn = -1.0; }
        else          { t = tw;          sgn = 1.0;  }
        const double rmax = PI_ - 0.01;
        if (t > rmax) t = rmax;
        const double f = sgn * t / ts;
        __builtin_nontemporal_store((float)(me * f), &out[obase + 1024 + l]);
    }
}

extern "C" void kernel_launch(void* const* d_in, const int* in_sizes, int n_in,
                              void* d_out, int out_size, void* d_ws, size_t ws_size,
                              hipStream_t stream)
{
    const float* Sg     = (const float*)d_in[0];
    const float* Pg     = (const float*)d_in[1];
    const float* phig   = (const float*)d_in[2];
    const float* piphig = (const float*)d_in[3];
    float* out = (float*)d_out;

    const int total = in_sizes[0] / 1024;   // B*N = 32768 matrices

    leapfrog_fused<<<(total + 15) / 16, 1024, 0, stream>>>(Sg, Pg, phig, piphig, out, total);
}

// Round 17
// 74.199 us; speedup vs baseline: 2.0738x; 2.0738x over previous
//
#include <hip/hip_runtime.h>
#include <hip/hip_bf16.h>
#include <math.h>

// Leapfrog on SPD(32), eigh-free, inverse-free, barrier-free MFMA version.
//   U = S·P ; Ut = P·S (independent) ; H = U·U (= S·P·S·P = S·G)
//   M = 0.02·U - 2e-4·H  (= 2DT·S·pi_half)
//   E = exp(M^T) Taylor-3, first stage in f32 VALU: X3 = I + M/3,
//   then X2 = I + (1/2)M^T·X3, X1 = I + M^T·X2 (2 MFMA stages)
//   Sigma_new = sym(S·E) + 1e-8 I
// R16 structure (16-wave blocks + LDS-bounce fence) with the spill bug
// fixed: launch_bounds(1024,4) -> VGPR budget 128, compiler's natural ~64
// -> HW residency 8 waves/SIMD, 2 blocks/CU by LDS (67.6KB) = 32 waves/CU.
// R16 A/B evidence: 16-wave blocks raised occupancy 37->75% (dispatch
// churn WAS the occupancy limiter) but launch_bounds(1024,8) forced
// VGPR=32 -> +400MB scratch traffic -> 154us. This round keeps the
// occupancy win, drops the cap.
// LDS transpose-bounce requires __threadfence_block() between writes and
// reads (R15: compiler legally reorders cross-lane DS ops otherwise).
// All validated pieces: trunc v_perm packs, contiguous nt stores, cached
// loads, U^2-head, Taylor-3 with f32 first stage, independent 3-chain
// tail, v_permlane32_swap_b32 (swap32(x,y): x.lanes[32:63]<->y.lanes[0:31]).

typedef unsigned int u32;
typedef __attribute__((ext_vector_type(8))) short bf16x8;
typedef __attribute__((ext_vector_type(16))) float f32x16;

#define FPAD 33   // f32 row stride of sym buffer: 33 mod 32 == 1 -> conflict-free

union U4 { u32 u[4]; bf16x8 v; };

__device__ __forceinline__ bf16x8 mk8(u32 a, u32 b, u32 c, u32 d) {
    U4 t; t.u[0] = a; t.u[1] = b; t.u[2] = c; t.u[3] = d; return t.v;
}

// pack bf16(x),bf16(y) (truncated) into one u32: low16 = x, high16 = y
__device__ __forceinline__ u32 pkt(float x, float y) {
    return __builtin_amdgcn_perm(__float_as_uint(y), __float_as_uint(x), 0x07060302u);
}

__device__ __forceinline__ float asfloat(u32 b) {
    union { u32 u; float f; } c; c.u = b; return c.f;
}

__device__ __forceinline__ f32x16 zero16() {
    f32x16 z;
#pragma unroll
    for (int i = 0; i < 16; ++i) z[i] = 0.f;
    return z;
}

struct Frag8 { u32 r[8]; };

// v_permlane32_swap_b32: x.lanes[32:63] <-> y.lanes[0:31]
__device__ __forceinline__ void swap32(u32& x, u32& y) {
    asm("v_permlane32_swap_b32 %0, %1" : "+v"(x), "+v"(y));
}

// packed-pair regs p[8] (D-layout pairs) -> B-fragment order.
// swap32(x=p[lo], y=p[hi]):
//   x.lanes[32:63] <- old y.lanes[0:31]  = p[hi] of lane l-32   -> x == B.r[lo]
//   y.lanes[0:31]  <- old x.lanes[32:63] = p[lo] of lane l+32   -> y == B.r[hi]
__device__ __forceinline__ void xchg(const u32* p, Frag8& B) {
    { u32 x = p[0], y = p[2]; swap32(x, y); B.r[0] = x; B.r[2] = y; }
    { u32 x = p[1], y = p[3]; swap32(x, y); B.r[1] = x; B.r[3] = y; }
    { u32 x = p[4], y = p[6]; swap32(x, y); B.r[4] = x; B.r[6] = y; }
    { u32 x = p[5], y = p[7]; swap32(x, y); B.r[5] = x; B.r[7] = y; }
}

// D-layout f32x16 -> bf16 B-fragment, trunc pack (no scale)
__device__ __forceinline__ void bconv(const f32x16& X, Frag8& B) {
    u32 p[8];
#pragma unroll
    for (int i = 0; i < 8; ++i) p[i] = pkt(X[2*i], X[2*i+1]);
    xchg(p, B);
}

// D-layout f32x16 -> bf16 B-fragment, pre-scaled, trunc pack
__device__ __forceinline__ void bconv_s(const f32x16& X, float scale, Frag8& B) {
    u32 p[8];
#pragma unroll
    for (int i = 0; i < 8; ++i) p[i] = pkt(X[2*i] * scale, X[2*i+1] * scale);
    xchg(p, B);
}

// D-layout f32x16 -> exact hi/lo split bf16 B-fragments
__device__ __forceinline__ void bconv_split(const f32x16& X, Frag8& Bh, Frag8& Bl) {
    u32 p[8], q[8];
#pragma unroll
    for (int i = 0; i < 8; ++i) {
        const float x = X[2*i], y = X[2*i+1];
        p[i] = pkt(x, y);
        const float lx = x - asfloat(p[i] << 16);
        const float ly = y - asfloat(p[i] & 0xffff0000u);
        q[i] = pkt(lx, ly);
    }
    xchg(p, Bh);
    xchg(q, Bl);
}

__device__ __forceinline__ f32x16 MFMA1(const u32* a, const u32* b, f32x16 acc) {
    return __builtin_amdgcn_mfma_f32_32x32x16_bf16(
        mk8(a[0], a[1], a[2], a[3]), mk8(b[0], b[1], b[2], b[3]), acc, 0, 0, 0);
}

__device__ __forceinline__ f32x16 matmul(const Frag8& A, const Frag8& B, f32x16 acc) {
    acc = MFMA1(A.r,     B.r,     acc);   // k = 0..15
    acc = MFMA1(A.r + 4, B.r + 4, acc);   // k = 16..31
    return acc;
}

__global__ __launch_bounds__(1024, 4)
void leapfrog_fused(const float* __restrict__ Sg, const float* __restrict__ Pg,
                    const float* __restrict__ phig, const float* __restrict__ piphig,
                    float* __restrict__ out, int total)
{
    __shared__ __align__(16) float symb[16 * 32 * FPAD];

    const int w  = threadIdx.x >> 6;          // 0..15
    const int l  = threadIdx.x & 63;
    const int bn = blockIdx.x * 16 + w;
    if (bn >= total) return;            // wave-uniform; kernel has no barriers

    float* sy = symb + w * 32 * FPAD;

    const int fr = l & 31;
    const int h  = l >> 5;
    const size_t gbase = (size_t)bn * 1024;

    // ---- fragment loads straight from global; phi prefetched alongside ----
    const float* Srow = Sg + gbase + fr * 32 + h * 8;
    const float* Prow = Pg + gbase + fr * 32 + h * 8;
    const float4 sv[4] = { *(const float4*)(Srow +  0), *(const float4*)(Srow +  4),
                           *(const float4*)(Srow + 16), *(const float4*)(Srow + 20) };
    const float4 pv[4] = { *(const float4*)(Prow +  0), *(const float4*)(Prow +  4),
                           *(const float4*)(Prow + 16), *(const float4*)(Prow + 20) };
    // phi inputs: lanes 0-2 each handle one component in the epilogue
    float phc = 0.f, qhc = 0.f;
    if (l < 3) { phc = phig[3 * bn + l]; qhc = piphig[3 * bn + l]; }

    Frag8 FS, FSl, FP;
#pragma unroll
    for (int i = 0; i < 4; ++i) {
        const float4 s = sv[i];
        const float4 p = pv[i];
        const u32 ha = pkt(s.x, s.y);
        const u32 hb = pkt(s.z, s.w);
        FS.r[2*i]   = ha;
        FS.r[2*i+1] = hb;
        const float lx = s.x - asfloat(ha << 16);
        const float ly = s.y - asfloat(ha & 0xffff0000u);
        const float lz = s.z - asfloat(hb << 16);
        const float lw = s.w - asfloat(hb & 0xffff0000u);
        FSl.r[2*i]   = pkt(lx, ly);
        FSl.r[2*i+1] = pkt(lz, lw);
        FP.r[2*i]   = pkt(p.x, p.y);
        FP.r[2*i+1] = pkt(p.z, p.w);
    }

    // identity in D-layout: row (i&3)+8*(i>>2)+4h, col fr
    f32x16 If;
#pragma unroll
    for (int i = 0; i < 16; ++i)
        If[i] = (((i & 3) + 8 * (i >> 2) + 4 * h) == fr) ? 1.f : 0.f;

    // ---- U = S·P ; Ut = P·S (independent chains) ; H = U·U = S·P·S·P ----
    f32x16 U  = matmul(FS, FP, zero16());
    f32x16 Ut = matmul(FP, FS, zero16());
    Frag8 BU;  bconv(U,  BU);
    Frag8 BUt; bconv(Ut, BUt);              // as A-operand represents U
    f32x16 H = matmul(BUt, BU, zero16());

    // ---- M = 2DT·U − 2DT²·H ;  X3 = I + M/3 (f32 VALU — free stage) ----
    f32x16 M, X;
#pragma unroll
    for (int i = 0; i < 16; ++i) {
        M[i] = 0.02f * U[i] - 2e-4f * H[i];
        X[i] = If[i] + (1.0f / 3.0f) * M[i];
    }
    Frag8 FM; bconv(M, FM);                 // A-frag of M^T

    // ---- X2 = I + (1/2)·M^T·X3 ; X1 = I + M^T·X2 (2 MFMA stages) ----
    {
        Frag8 BX; bconv_s(X, 0.5f, BX);
        X = matmul(FM, BX, If);
    }
    {
        Frag8 BX; bconv(X, BX);
        X = matmul(FM, BX, If);
    }

    // ---- Y^T = S·X, hi/lo split, three INDEPENDENT 2-MFMA chains ----
    Frag8 BE, BEl;
    bconv_split(X, BE, BEl);
    f32x16 Y1 = matmul(FS,  BE,  zero16());
    f32x16 Y2 = matmul(FSl, BE,  zero16());
    f32x16 Y3 = matmul(FS,  BEl, zero16());

    // ---- sym + eps·I via LDS bounce. Reads consume OTHER lanes' writes:
    //      invisible to per-thread alias analysis -> fence REQUIRED to
    //      stop read/write reordering (R15). DS pipe in-order per wave,
    //      regions per-wave -> fence suffices, no __syncthreads. ----
#pragma unroll
    for (int i = 0; i < 16; ++i) {
        const int r = (i & 3) + 8 * (i >> 2) + 4 * h;
        sy[r * FPAD + fr] = Y1[i] + Y2[i] + Y3[i];
    }
    __threadfence_block();                  // order bounce writes before reads
    const size_t obase = (size_t)bn * 1027;
#pragma unroll
    for (int k = 0; k < 16; ++k) {
        const int idx = k * 64 + l;
        const int r = idx >> 5, c = idx & 31;
        const float a = sy[r * FPAD + c];
        const float b = sy[c * FPAD + r];
        float v = 0.5f * (a + b);
        if (r == c) v += 1e-8f;
        __builtin_nontemporal_store(v, &out[obase + idx]);
    }

    // ---- fused phi retraction (lanes 0-2, double; floor-based mod 2pi) ----
    if (l < 3) {
        const double TWO_PI = 6.283185307179586476925287;
        const double PI_    = 3.141592653589793238462643;
        const double c0 = (double)__shfl(phc, 0, 64) + 0.01 * (double)__shfl(qhc, 0, 64);
        const double c1 = (double)__shfl(phc, 1, 64) + 0.01 * (double)__shfl(qhc, 1, 64);
        const double c2 = (double)__shfl(phc, 2, 64) + 0.01 * (double)__shfl(qhc, 2, 64);
        const double me = (l == 0) ? c0 : (l == 1) ? c1 : c2;
        const double theta = sqrt(c0 * c0 + c1 * c1 + c2 * c2);
        const double ts = theta > 1e-12 ? theta : 1e-12;
        const double k2 = floor(theta * (1.0 / TWO_PI));
        const double tw = theta - k2 * TWO_PI;          // fmod(theta, 2pi), theta >= 0
        double t, sgn;
        if (tw > PI_) { t = TWO_PI - tw; sgn = -1.0; }
        else          { t = tw;          sgn = 1.0;  }
        const double rmax = PI_ - 0.01;
        if (t > rmax) t = rmax;
        const double f = sgn * t / ts;
        __builtin_nontemporal_store((float)(me * f), &out[obase + 1024 + l]);
    }
}

extern "C" void kernel_launch(void* const* d_in, const int* in_sizes, int n_in,
                              void* d_out, int out_size, void* d_ws, size_t ws_size,
                              hipStream_t stream)
{
    const float* Sg     = (const float*)d_in[0];
    const float* Pg     = (const float*)d_in[1];
    const float* phig   = (const float*)d_in[2];
    const float* piphig = (const float*)d_in[3];
    float* out = (float*)d_out;

    const int total = in_sizes[0] / 1024;   // B*N = 32768 matrices

    leapfrog_fused<<<(total + 15) / 16, 1024, 0, stream>>>(Sg, Pg, phig, piphig, out, total);
}